// Round 2
// baseline (423.846 us; speedup 1.0000x reference)
//
#include <hip/hip_runtime.h>
#include <stdint.h>

// Kernel 1: compact the block-diagonal cos/sin of the gathered rotation
// matrices into tab[s*128 + 2k] = cos_k(pos[s]), tab[s*128 + 2k+1] = sin_k(pos[s]).
// R layout (MAX_S, 128, 128) row-major:
//   R[p, 2k,   2k] = c  -> elem offset p*16384 + 258*k
//   R[p, 2k+1, 2k] = s  -> elem offset p*16384 + 258*k + 128
__global__ void build_cs_table(const float* __restrict__ R,
                               const int* __restrict__ pos,
                               float* __restrict__ tab, int seq) {
    int idx = blockIdx.x * blockDim.x + threadIdx.x;
    int s = idx >> 6;          // sequence index
    int k = idx & 63;          // pair index
    if (s >= seq) return;
    long p = (long)pos[s];
    const float* rp = R + p * 16384;
    float c  = rp[258 * k];
    float sn = rp[258 * k + 128];
    tab[s * 128 + 2 * k]     = c;
    tab[s * 128 + 2 * k + 1] = sn;
}

// Kernel 2: vectorized rotation. Each thread handles 4 floats (2 pairs):
// one float4 load of X, one float4 load of the cos/sin table, one float4 store.
__global__ void rope_apply(const float* __restrict__ X,
                           const float* __restrict__ tab,
                           float* __restrict__ out,
                           int seq, long n4) {
    long i = (long)blockIdx.x * blockDim.x + threadIdx.x;
    if (i >= n4) return;
    long e   = i << 2;               // element offset (multiple of 4)
    int  d0  = (int)(e & 127);       // offset within d_k row
    long row = e >> 7;               // (b*H + h)*seq + s
    int  s   = (int)(row % seq);

    float4 x  = *(const float4*)(X + e);
    float4 cs = *(const float4*)(tab + (long)s * 128 + d0);
    float4 o;
    o.x = cs.x * x.x - cs.y * x.y;
    o.y = cs.y * x.x + cs.x * x.y;
    o.z = cs.z * x.z - cs.w * x.w;
    o.w = cs.w * x.z + cs.z * x.w;
    *(float4*)(out + e) = o;
}

// Fallback (workspace too small): gather cos/sin straight from R per thread.
__global__ void rope_direct(const float* __restrict__ X,
                            const float* __restrict__ R,
                            const int* __restrict__ pos,
                            float* __restrict__ out,
                            int seq, long n4) {
    long i = (long)blockIdx.x * blockDim.x + threadIdx.x;
    if (i >= n4) return;
    long e   = i << 2;
    int  d0  = (int)(e & 127);
    long row = e >> 7;
    int  s   = (int)(row % seq);
    long p   = (long)pos[s];
    const float* rp = R + p * 16384;

    int k0 = d0 >> 1;
    float c0 = rp[258 * k0];
    float s0 = rp[258 * k0 + 128];
    float c1 = rp[258 * (k0 + 1)];
    float s1 = rp[258 * (k0 + 1) + 128];

    float4 x = *(const float4*)(X + e);
    float4 o;
    o.x = c0 * x.x - s0 * x.y;
    o.y = s0 * x.x + c0 * x.y;
    o.z = c1 * x.z - s1 * x.w;
    o.w = s1 * x.z + c1 * x.w;
    *(float4*)(out + e) = o;
}

extern "C" void kernel_launch(void* const* d_in, const int* in_sizes, int n_in,
                              void* d_out, int out_size, void* d_ws, size_t ws_size,
                              hipStream_t stream) {
    const float* X   = (const float*)d_in[0];      // fp32 (B,H,S,D)
    const int*   pos = (const int*)d_in[1];        // int32 (S,)
    const float* R   = (const float*)d_in[2];      // fp32 (MAX_S,128,128)
    float* out       = (float*)d_out;

    const long n   = (long)in_sizes[0];            // B*H*S*D
    const int  seq = in_sizes[1];                  // S
    const long n4  = n >> 2;                       // threads for apply kernel

    const size_t tab_bytes = (size_t)seq * 128 * sizeof(float);

    const int blk = 256;
    if (ws_size >= tab_bytes) {
        float* tab = (float*)d_ws;
        int t1 = seq * 64;
        build_cs_table<<<(t1 + blk - 1) / blk, blk, 0, stream>>>(R, pos, tab, seq);
        rope_apply<<<(int)((n4 + blk - 1) / blk), blk, 0, stream>>>(X, tab, out, seq, n4);
    } else {
        rope_direct<<<(int)((n4 + blk - 1) / blk), blk, 0, stream>>>(X, R, pos, out, seq, n4);
    }
}